// Round 6
// baseline (244.392 us; speedup 1.0000x reference)
//
#include <hip/hip_runtime.h>

#define NUM_SEGS 1024
#define CHUNK_LOG 13
#define CHUNK (1 << CHUNK_LOG)   // 8192 elements per chunk
#define SUBCH 2                  // chunks per block (block span = 16384)
#define SUPER (CHUNK * SUBCH)
#define BLK 256                  // 4 waves/block; 1024 blocks -> 4 blocks/CU
#define NWAVE (BLK / 64)
#define DEPTH 8                  // float4-triples per thread per chunk (8*1024=8192)
#define SEGBLK 256

__device__ __forceinline__ float waveReduceSumF(float v) {
#pragma unroll
    for (int off = 32; off > 0; off >>= 1) v += __shfl_down(v, off, 64);
    return v;
}
__device__ __forceinline__ double waveReduceSumD(double v) {
#pragma unroll
    for (int off = 32; off > 0; off >>= 1) v += __shfl_down(v, off, 64);
    return v;
}
__device__ __forceinline__ unsigned waveReduceSumU(unsigned v) {
#pragma unroll
    for (int off = 32; off > 0; off >>= 1) v += __shfl_down(v, off, 64);
    return v;
}
__device__ __forceinline__ int waveReduceMaxI(int v) {
#pragma unroll
    for (int off = 32; off > 0; off >>= 1) {
        const int o = __shfl_down(v, off, 64);
        v = o > v ? o : v;
    }
    return v;
}

// ---------------- init: zero accumulators (ws is poisoned 0xAA every call) ---
__global__ void init_kernel(unsigned* __restrict__ seg_cnt,
                            float* __restrict__ csums, int nChunks,
                            unsigned* __restrict__ obs,
                            double* __restrict__ loss1,
                            double* __restrict__ loss2,
                            unsigned* __restrict__ done) {
    const int t = blockIdx.x * blockDim.x + threadIdx.x;
    if (t < NUM_SEGS) seg_cnt[t] = 0u;
    if (t < nChunks) csums[t] = 0.f;  // needed only by the tail path
    if (t == 0) { obs[0] = 0u; loss1[0] = 0.0; loss2[0] = 0.0; done[0] = 0u; }
}

// ---------------- pass 1: deep in-flight streaming ---------------------------
// Per chunk: each thread issues ALL 24 loads (8 float4-triples = 24KB/wave)
// into statically-indexed register arrays BEFORE consuming any -> one
// graduated waitcnt chain, ~24 loads in flight per wave instead of 3.
// Block owns its 2 chunks exclusively -> csums is a plain store (no atomic).
// Exactly one __syncthreads() in the whole kernel.
__global__ __launch_bounds__(BLK, 4) void pass1_kernel(
    const float* __restrict__ outs, const int* __restrict__ te,
    const int* __restrict__ tt, int N, int nChunks,
    float* __restrict__ csums, unsigned* __restrict__ seg_cnt,
    unsigned* __restrict__ obs, double* __restrict__ loss1) {
    __shared__ unsigned hist[NUM_SEGS];
    __shared__ float redC[SUBCH][NWAVE];
    __shared__ float redF[NWAVE];
    __shared__ unsigned redU[NWAVE];

    for (int t = threadIdx.x; t < NUM_SEGS; t += BLK) hist[t] = 0u;
    __syncthreads();  // hist zeroed (counted as part of the single barrier pair)

    const int lane = threadIdx.x & 63;
    const int wid = threadIdx.x >> 6;
    const int superBase = blockIdx.x * SUPER;

    float sumOE = 0.f;
    unsigned cntE = 0u;

    if (superBase + SUPER <= N) {
        const int i0 = superBase + ((int)threadIdx.x << 2);
#pragma unroll
        for (int k = 0; k < SUBCH; ++k) {
            // phase A: issue all 24 loads (static register arrays)
            float4 O[DEPTH];
            int4 E[DEPTH], S[DEPTH];
#pragma unroll
            for (int j = 0; j < DEPTH; ++j) {
                const int idx = i0 + k * CHUNK + j * (BLK * 4);
                O[j] = *reinterpret_cast<const float4*>(outs + idx);
                E[j] = *reinterpret_cast<const int4*>(te + idx);
                S[j] = *reinterpret_cast<const int4*>(tt + idx);
            }
            // phase B: consume
            float s = 0.f;
#pragma unroll
            for (int j = 0; j < DEPTH; ++j) {
                const float4 o = O[j];
                const int4 ev = E[j];
                const int4 sv = S[j];
                s += (__expf(o.x) + __expf(o.y)) + (__expf(o.z) + __expf(o.w));
                const int s0 = sv.x < 0 ? -sv.x : sv.x;
                const int s1 = sv.y < 0 ? -sv.y : sv.y;
                const int s2 = sv.z < 0 ? -sv.z : sv.z;
                const int s3 = sv.w < 0 ? -sv.w : sv.w;
                if (ev.x > 0) { cntE++; sumOE += o.x; atomicAdd(&hist[s0], 1u); }
                if (ev.y > 0) { cntE++; sumOE += o.y; atomicAdd(&hist[s1], 1u); }
                if (ev.z > 0) { cntE++; sumOE += o.z; atomicAdd(&hist[s2], 1u); }
                if (ev.w > 0) { cntE++; sumOE += o.w; atomicAdd(&hist[s3], 1u); }
            }
            const float w = waveReduceSumF(s);
            if (lane == 0) redC[k][wid] = w;
        }
    } else {
        // tail path (not hit for N = 16M): accumulate via zeroed global csums
        if (lane == 0) {
#pragma unroll
            for (int k = 0; k < SUBCH; ++k) redC[k][wid] = 0.f;
        }
        for (int k = 0; k < SUBCH; ++k) {
            const int cbase = superBase + k * CHUNK;
            if (cbase >= N) break;
            const int end = (cbase + CHUNK < N) ? cbase + CHUNK : N;
            float s = 0.f;
            for (int i = cbase + (int)threadIdx.x; i < end; i += BLK) {
                const float o = outs[i];
                const int e = te[i];
                int sg = tt[i]; sg = sg < 0 ? -sg : sg;
                s += __expf(o);
                if (e > 0) { cntE++; sumOE += o; atomicAdd(&hist[sg], 1u); }
            }
            const float w = waveReduceSumF(s);
            if (lane == 0 && w != 0.f) atomicAdd(&csums[cbase >> CHUNK_LOG], w);
        }
    }

    // E-stat wave partials (before the single barrier)
    const float wOE = waveReduceSumF(sumOE);
    const unsigned wC = waveReduceSumU(cntE);
    if (lane == 0) { redF[wid] = wOE; redU[wid] = wC; }

    __syncthreads();  // hist complete + all red* slots written

    // flush per-block histogram
    for (int t = threadIdx.x; t < NUM_SEGS; t += BLK) {
        const unsigned h = hist[t];
        if (h) atomicAdd(&seg_cnt[t], h);
    }

    if (threadIdx.x == 0) {
        // csums plain store (fast path; block exclusively owns its chunks)
        if (superBase + SUPER <= N) {
            const int c0 = superBase >> CHUNK_LOG;
#pragma unroll
            for (int k = 0; k < SUBCH; ++k) {
                float cs = 0.f;
#pragma unroll
                for (int j = 0; j < NWAVE; ++j) cs += redC[k][j];
                csums[c0 + k] = cs;
            }
        }
        float oe = 0.f; unsigned c = 0u;
#pragma unroll
        for (int j = 0; j < NWAVE; ++j) { oe += redF[j]; c += redU[j]; }
        atomicAdd(loss1, (double)oe);
        atomicAdd(obs, c);
    }
}

// ---------------- pass 2 (fused): backward last-idx search + prefix + finalize
// Block t: scan chunks from the end until segment t is found (random data:
// always the last chunk, L2-hot for all 1024 blocks). Then fp64 prefix over
// csums[0..c), fp32 in-chunk exp-sum to LI, V*cnt, ticket-finalize.
__global__ __launch_bounds__(SEGBLK) void seg_final_kernel(
    const float* __restrict__ outs, const int* __restrict__ tt,
    const float* __restrict__ csums, const unsigned* __restrict__ seg_cnt,
    const double* __restrict__ loss1, double* __restrict__ loss2,
    const unsigned* __restrict__ obs, unsigned* __restrict__ done,
    float* __restrict__ out, int N, int nChunks) {
    __shared__ double redD[SEGBLK / 64];
    __shared__ float redF[SEGBLK / 64];
    __shared__ int redI[SEGBLK / 64];
    __shared__ int s_li;

    const int t = blockIdx.x;
    const unsigned cnt = seg_cnt[t];
    const int lane = threadIdx.x & 63, wid = threadIdx.x >> 6;

    if (cnt != 0u) {  // cnt==0 segments contribute 0
        // ---- backward search for the last occurrence of segment t ----
        int c = nChunks - 1;
        int LI = -1;
        for (;;) {
            const int base = c << CHUNK_LOG;
            const int end = (base + CHUNK < N) ? base + CHUNK : N;
            const int span = end - base;
            const int qspan = span & ~3;  // int4-aligned portion
            int li = -1;
            for (int i = base + ((int)threadIdx.x << 2); i < base + qspan;
                 i += SEGBLK * 4) {
                const int4 sv = *reinterpret_cast<const int4*>(tt + i);
                const int s0 = sv.x < 0 ? -sv.x : sv.x;
                const int s1 = sv.y < 0 ? -sv.y : sv.y;
                const int s2 = sv.z < 0 ? -sv.z : sv.z;
                const int s3 = sv.w < 0 ? -sv.w : sv.w;
                if (s3 == t) li = i + 3;
                else if (s2 == t) li = i + 2;
                else if (s1 == t) li = i + 1;
                else if (s0 == t) li = i;
                // ascending i => later assignment always larger
            }
            for (int i = base + qspan + (int)threadIdx.x; i < end; i += SEGBLK) {
                int s = tt[i]; s = s < 0 ? -s : s;
                if (s == t && i > li) li = i;
            }
            li = waveReduceMaxI(li);
            if (lane == 0) redI[wid] = li;
            __syncthreads();
            if (threadIdx.x == 0) {
                int m = redI[0];
#pragma unroll
                for (int j = 1; j < SEGBLK / 64; ++j) m = redI[j] > m ? redI[j] : m;
                s_li = m;
            }
            __syncthreads();
            LI = s_li;
            if (LI >= 0 || --c < 0) break;
        }

        if (LI >= 0) {
            // fp64 exclusive prefix of chunk sums [0, c)
            double p = 0.0;
            for (int j = threadIdx.x; j < c; j += SEGBLK) p += (double)csums[j];
            p = waveReduceSumD(p);
            if (lane == 0) redD[wid] = p;

            // fp32 in-chunk exp-sum up to and including LI
            const int base = c << CHUNK_LOG;
            float fs = 0.f;
            for (int i = base + (int)threadIdx.x; i <= LI; i += SEGBLK)
                fs += __expf(outs[i]);
            fs = waveReduceSumF(fs);
            if (lane == 0) redF[wid] = fs;
            __syncthreads();
            if (threadIdx.x == 0) {
                double pre = 0.0;
                float fsum = 0.f;
#pragma unroll
                for (int j = 0; j < SEGBLK / 64; ++j) { pre += redD[j]; fsum += redF[j]; }
                double sm = log(pre + (double)fsum);  // monotone cumsum => max at LI
                if (sm < 0.0) sm = 0.0;               // jnp.maximum(..., 0.0)
                atomicAdd(loss2, sm * (double)cnt);
            }
        }
    }

    // done-ticket: last block finalizes (no separate final kernel)
    if (threadIdx.x == 0) {
        __threadfence();
        const unsigned d = atomicAdd(done, 1u);
        if (d == (unsigned)(gridDim.x - 1)) {
            const double l2 = atomicAdd(loss2, 0.0);            // atomic read
            const double l1 = *(volatile const double*)loss1;   // prior dispatch
            const unsigned o = *(volatile const unsigned*)obs;
            out[0] = (float)((l2 - l1) / (double)o);
        }
    }
}

extern "C" void kernel_launch(void* const* d_in, const int* in_sizes, int n_in,
                              void* d_out, int out_size, void* d_ws, size_t ws_size,
                              hipStream_t stream) {
    const float* outs = (const float*)d_in[0];
    const int* te = (const int*)d_in[1];
    const int* tt = (const int*)d_in[2];
    const int N = in_sizes[0];
    float* out = (float*)d_out;

    const int nChunks = (N + CHUNK - 1) / CHUNK;

    char* ws = (char*)d_ws;
    double* d_loss1 = (double*)ws;                        // 1 double
    double* d_loss2 = d_loss1 + 1;                        // 1 double
    float* d_csums = (float*)(ws + 16);                   // nChunks floats
    unsigned* d_segcnt = (unsigned*)(d_csums + nChunks);  // NUM_SEGS u32
    unsigned* d_obs = d_segcnt + NUM_SEGS;
    unsigned* d_done = d_obs + 1;

    const int initThreads = (nChunks > NUM_SEGS ? nChunks : NUM_SEGS);
    init_kernel<<<(initThreads + 255) / 256, 256, 0, stream>>>(
        d_segcnt, d_csums, nChunks, d_obs, d_loss1, d_loss2, d_done);
    const int nSuper = (N + SUPER - 1) / SUPER;
    pass1_kernel<<<nSuper, BLK, 0, stream>>>(outs, te, tt, N, nChunks, d_csums,
                                             d_segcnt, d_obs, d_loss1);
    seg_final_kernel<<<NUM_SEGS, SEGBLK, 0, stream>>>(
        outs, tt, d_csums, d_segcnt, d_loss1, d_loss2, d_obs, d_done, out, N,
        nChunks);
}

// Round 7
// 227.827 us; speedup vs baseline: 1.0727x; 1.0727x over previous
//
#include <hip/hip_runtime.h>

#define NUM_SEGS 1024
#define CHUNK_LOG 13
#define CHUNK (1 << CHUNK_LOG)   // 8192 elements per chunk
#define SUBCH 4                  // chunks per block (superchunk = 32768)
#define SUPER (CHUNK * SUBCH)
#define BLK 512                  // 8 waves/block; grid 512 -> 2 blocks/CU
#define NWAVE (BLK / 64)
#define NBATCH 16                // batches/thread (1 float4-triple each)
#define PDEPTH 6                 // software-pipeline depth (triples in flight)
#define SEGBLK 256

__device__ __forceinline__ float waveReduceSumF(float v) {
#pragma unroll
    for (int off = 32; off > 0; off >>= 1) v += __shfl_down(v, off, 64);
    return v;
}
__device__ __forceinline__ double waveReduceSumD(double v) {
#pragma unroll
    for (int off = 32; off > 0; off >>= 1) v += __shfl_down(v, off, 64);
    return v;
}
__device__ __forceinline__ unsigned waveReduceSumU(unsigned v) {
#pragma unroll
    for (int off = 32; off > 0; off >>= 1) v += __shfl_down(v, off, 64);
    return v;
}
__device__ __forceinline__ int waveReduceMaxI(int v) {
#pragma unroll
    for (int off = 32; off > 0; off >>= 1) {
        const int o = __shfl_down(v, off, 64);
        v = o > v ? o : v;
    }
    return v;
}

// ---------------- init: zero accumulators (ws is poisoned 0xAA every call) ---
__global__ void init_kernel(unsigned* __restrict__ seg_cnt,
                            float* __restrict__ csums, int nChunks,
                            unsigned* __restrict__ obs,
                            double* __restrict__ loss1,
                            double* __restrict__ loss2,
                            unsigned* __restrict__ done) {
    const int t = blockIdx.x * blockDim.x + threadIdx.x;
    if (t < NUM_SEGS) seg_cnt[t] = 0u;
    if (t < nChunks) csums[t] = 0.f;
    if (t == 0) { obs[0] = 0u; loss1[0] = 0.0; loss2[0] = 0.0; done[0] = 0u; }
}

// ---------------- pass 1: depth-6 software-pipelined streaming ---------------
// r5's proven sched_barrier mechanism (the only variant that measurably raised
// per-wave MLP: VGPR 20->48, 2x per-wave rate) extended to PDEPTH=6: rotating
// 6-triple register buffer, fully unrolled, loads for batch b+6 issued and
// PINNED (sched_barrier) before batch b is consumed -> ~18 loads (18KB) in
// flight per wave at steady state.
__global__ __launch_bounds__(BLK, 2) void pass1_kernel(
    const float* __restrict__ outs, const int* __restrict__ te,
    const int* __restrict__ tt, int N, int nChunks,
    float* __restrict__ csums, unsigned* __restrict__ seg_cnt,
    unsigned* __restrict__ obs, double* __restrict__ loss1) {
    __shared__ unsigned hist[NUM_SEGS];
    __shared__ float redF[NWAVE];
    __shared__ unsigned redU[NWAVE];

    for (int t = threadIdx.x; t < NUM_SEGS; t += BLK) hist[t] = 0u;
    __syncthreads();

    const int lane = threadIdx.x & 63;
    const int wid = threadIdx.x >> 6;
    const int superBase = blockIdx.x * SUPER;

    float sE[SUBCH] = {0.f, 0.f, 0.f, 0.f};  // batch b -> chunk b>>2 (static)
    float sumOE = 0.f;
    unsigned cntE = 0u;

    if (superBase + SUPER <= N) {
        const int i0 = superBase + ((int)threadIdx.x << 2);
        float4 O[PDEPTH];
        int4 E[PDEPTH], S[PDEPTH];

#define LOADB(b, sl)                                                        \
    do {                                                                    \
        const int _i = i0 + (b) * (BLK * 4);                                \
        O[sl] = *reinterpret_cast<const float4*>(outs + _i);                \
        E[sl] = *reinterpret_cast<const int4*>(te + _i);                    \
        S[sl] = *reinterpret_cast<const int4*>(tt + _i);                    \
    } while (0)

        // prologue: fill the pipeline (18 loads in flight)
#pragma unroll
        for (int b = 0; b < PDEPTH; ++b) LOADB(b, b);

#pragma unroll
        for (int b = 0; b < NBATCH; ++b) {
            if (b + PDEPTH < NBATCH) LOADB(b + PDEPTH, (b + PDEPTH) % PDEPTH);
            __builtin_amdgcn_sched_barrier(0);  // pin issue above consume
            {
                const int sl = b % PDEPTH;  // compile-time (unrolled)
                const float4 o = O[sl];
                const int4 ev = E[sl];
                const int4 sv = S[sl];
                sE[b >> 2] += (__expf(o.x) + __expf(o.y)) +
                              (__expf(o.z) + __expf(o.w));
                const int s0 = sv.x < 0 ? -sv.x : sv.x;
                const int s1 = sv.y < 0 ? -sv.y : sv.y;
                const int s2 = sv.z < 0 ? -sv.z : sv.z;
                const int s3 = sv.w < 0 ? -sv.w : sv.w;
                if (ev.x > 0) { cntE++; sumOE += o.x; atomicAdd(&hist[s0], 1u); }
                if (ev.y > 0) { cntE++; sumOE += o.y; atomicAdd(&hist[s1], 1u); }
                if (ev.z > 0) { cntE++; sumOE += o.z; atomicAdd(&hist[s2], 1u); }
                if (ev.w > 0) { cntE++; sumOE += o.w; atomicAdd(&hist[s3], 1u); }
            }
        }
#undef LOADB

        // per-wave chunk-sum flush: one float atomic per (wave, chunk)
        const int c0 = superBase >> CHUNK_LOG;
#pragma unroll
        for (int k = 0; k < SUBCH; ++k) {
            const float w = waveReduceSumF(sE[k]);
            if (lane == 0) atomicAdd(&csums[c0 + k], w);
        }
    } else {
        // tail path (not hit for N = 16M)
        for (int k = 0; k < SUBCH; ++k) {
            const int cbase = superBase + k * CHUNK;
            if (cbase >= N) break;
            const int end = (cbase + CHUNK < N) ? cbase + CHUNK : N;
            float s = 0.f;
            for (int i = cbase + (int)threadIdx.x; i < end; i += BLK) {
                const float o = outs[i];
                const int e = te[i];
                int sg = tt[i]; sg = sg < 0 ? -sg : sg;
                s += __expf(o);
                if (e > 0) { cntE++; sumOE += o; atomicAdd(&hist[sg], 1u); }
            }
            const float w = waveReduceSumF(s);
            if (lane == 0 && w != 0.f) atomicAdd(&csums[cbase >> CHUNK_LOG], w);
        }
    }

    __syncthreads();  // the only mid-kernel block barrier: hist complete

    for (int t = threadIdx.x; t < NUM_SEGS; t += BLK) {
        const unsigned h = hist[t];
        if (h) atomicAdd(&seg_cnt[t], h);
    }

    // block-reduce E stats
    const float wOE = waveReduceSumF(sumOE);
    const unsigned wC = waveReduceSumU(cntE);
    if (lane == 0) { redF[wid] = wOE; redU[wid] = wC; }
    __syncthreads();
    if (threadIdx.x == 0) {
        float oe = 0.f; unsigned c = 0u;
#pragma unroll
        for (int j = 0; j < NWAVE; ++j) { oe += redF[j]; c += redU[j]; }
        atomicAdd(loss1, (double)oe);
        atomicAdd(obs, c);
    }
}

// ---------------- pass 2 (fused): backward last-idx search + prefix + finalize
__global__ __launch_bounds__(SEGBLK) void seg_final_kernel(
    const float* __restrict__ outs, const int* __restrict__ tt,
    const float* __restrict__ csums, const unsigned* __restrict__ seg_cnt,
    const double* __restrict__ loss1, double* __restrict__ loss2,
    const unsigned* __restrict__ obs, unsigned* __restrict__ done,
    float* __restrict__ out, int N, int nChunks) {
    __shared__ double redD[SEGBLK / 64];
    __shared__ float redF[SEGBLK / 64];
    __shared__ int redI[SEGBLK / 64];
    __shared__ int s_li;

    const int t = blockIdx.x;
    const unsigned cnt = seg_cnt[t];
    const int lane = threadIdx.x & 63, wid = threadIdx.x >> 6;

    if (cnt != 0u) {  // cnt==0 segments contribute 0
        // ---- backward search for the last occurrence of segment t ----
        int c = nChunks - 1;
        int LI = -1;
        for (;;) {
            const int base = c << CHUNK_LOG;
            const int end = (base + CHUNK < N) ? base + CHUNK : N;
            const int span = end - base;
            const int qspan = span & ~3;  // int4-aligned portion
            int li = -1;
            for (int i = base + ((int)threadIdx.x << 2); i < base + qspan;
                 i += SEGBLK * 4) {
                const int4 sv = *reinterpret_cast<const int4*>(tt + i);
                const int s0 = sv.x < 0 ? -sv.x : sv.x;
                const int s1 = sv.y < 0 ? -sv.y : sv.y;
                const int s2 = sv.z < 0 ? -sv.z : sv.z;
                const int s3 = sv.w < 0 ? -sv.w : sv.w;
                if (s3 == t) li = i + 3;
                else if (s2 == t) li = i + 2;
                else if (s1 == t) li = i + 1;
                else if (s0 == t) li = i;
                // ascending i => later assignment always larger
            }
            for (int i = base + qspan + (int)threadIdx.x; i < end; i += SEGBLK) {
                int s = tt[i]; s = s < 0 ? -s : s;
                if (s == t && i > li) li = i;
            }
            li = waveReduceMaxI(li);
            if (lane == 0) redI[wid] = li;
            __syncthreads();
            if (threadIdx.x == 0) {
                int m = redI[0];
#pragma unroll
                for (int j = 1; j < SEGBLK / 64; ++j) m = redI[j] > m ? redI[j] : m;
                s_li = m;
            }
            __syncthreads();
            LI = s_li;
            if (LI >= 0 || --c < 0) break;
        }

        if (LI >= 0) {
            // fp64 exclusive prefix of chunk sums [0, c)
            double p = 0.0;
            for (int j = threadIdx.x; j < c; j += SEGBLK) p += (double)csums[j];
            p = waveReduceSumD(p);
            if (lane == 0) redD[wid] = p;

            // fp32 in-chunk exp-sum up to and including LI
            const int base = c << CHUNK_LOG;
            float fs = 0.f;
            for (int i = base + (int)threadIdx.x; i <= LI; i += SEGBLK)
                fs += __expf(outs[i]);
            fs = waveReduceSumF(fs);
            if (lane == 0) redF[wid] = fs;
            __syncthreads();
            if (threadIdx.x == 0) {
                double pre = 0.0;
                float fsum = 0.f;
#pragma unroll
                for (int j = 0; j < SEGBLK / 64; ++j) { pre += redD[j]; fsum += redF[j]; }
                double sm = log(pre + (double)fsum);  // monotone cumsum => max at LI
                if (sm < 0.0) sm = 0.0;               // jnp.maximum(..., 0.0)
                atomicAdd(loss2, sm * (double)cnt);
            }
        }
    }

    // done-ticket: last block finalizes (no separate final kernel)
    if (threadIdx.x == 0) {
        __threadfence();
        const unsigned d = atomicAdd(done, 1u);
        if (d == (unsigned)(gridDim.x - 1)) {
            const double l2 = atomicAdd(loss2, 0.0);            // atomic read
            const double l1 = *(volatile const double*)loss1;   // prior dispatch
            const unsigned o = *(volatile const unsigned*)obs;
            out[0] = (float)((l2 - l1) / (double)o);
        }
    }
}

extern "C" void kernel_launch(void* const* d_in, const int* in_sizes, int n_in,
                              void* d_out, int out_size, void* d_ws, size_t ws_size,
                              hipStream_t stream) {
    const float* outs = (const float*)d_in[0];
    const int* te = (const int*)d_in[1];
    const int* tt = (const int*)d_in[2];
    const int N = in_sizes[0];
    float* out = (float*)d_out;

    const int nChunks = (N + CHUNK - 1) / CHUNK;

    char* ws = (char*)d_ws;
    double* d_loss1 = (double*)ws;                        // 1 double
    double* d_loss2 = d_loss1 + 1;                        // 1 double
    float* d_csums = (float*)(ws + 16);                   // nChunks floats
    unsigned* d_segcnt = (unsigned*)(d_csums + nChunks);  // NUM_SEGS u32
    unsigned* d_obs = d_segcnt + NUM_SEGS;
    unsigned* d_done = d_obs + 1;

    const int initThreads = (nChunks > NUM_SEGS ? nChunks : NUM_SEGS);
    init_kernel<<<(initThreads + 255) / 256, 256, 0, stream>>>(
        d_segcnt, d_csums, nChunks, d_obs, d_loss1, d_loss2, d_done);
    const int nSuper = (N + SUPER - 1) / SUPER;
    pass1_kernel<<<nSuper, BLK, 0, stream>>>(outs, te, tt, N, nChunks, d_csums,
                                             d_segcnt, d_obs, d_loss1);
    seg_final_kernel<<<NUM_SEGS, SEGBLK, 0, stream>>>(
        outs, tt, d_csums, d_segcnt, d_loss1, d_loss2, d_obs, d_done, out, N,
        nChunks);
}